// Round 1
// 447.897 us; speedup vs baseline: 1.0817x; 1.0817x over previous
//
#include <hip/hip_runtime.h>
#include <hip/hip_bf16.h>
#include <math.h>

#define BN 256
#define NN 2048
#define CC 64
#define NCH 8   // chunks per batch row: 256 rows per chunk

// workspace float offsets (no memset needed: every region is written before read)
#define WS_SUMQ 0                              // B*NCH*64  per-chunk masked q sums
#define WS_SUMM (WS_SUMQ + BN * NCH * 64)      // B*NCH     per-chunk mask sums
#define WS_V    (WS_SUMM + BN * NCH)           // B*NCH*64  per-chunk p*v partials
#define WS_S    (WS_V + BN * NCH * 64)         // B*NCH*8   per-chunk p sums
#define WS_MASK (WS_S + BN * NCH * 8)          // B*2048    compact mask column

typedef __bf16 bf16x8 __attribute__((ext_vector_type(8)));
typedef float f32x4 __attribute__((ext_vector_type(4)));

// ---------------- K1: masked pool over N (per-chunk partials, 8-deep load batches) ----
// 2048 blocks (B*8) x 256 thr -> 32 waves/CU grid headroom. Each thread: 16 rows,
// loads batched 8 deep (8 float4 + 8 mask dwords issued before any FMA) so each
// wave keeps ~8KB in flight -> latency-hiding instead of the old 1.25 TB/s crawl.
__global__ __launch_bounds__(256) void k_pool(const float* __restrict__ qd,
                                              const float* __restrict__ qm,
                                              float* __restrict__ ws) {
    const int b = blockIdx.x >> 3, chunk = blockIdx.x & 7;
    const int tid = threadIdx.x;
    const int r = tid >> 4, c4 = tid & 15;
    const float* qb = qd + (size_t)b * NN * CC;
    const float* mb = qm + (size_t)b * NN * CC;
    float* wmask = ws + WS_MASK + (size_t)b * NN;
    const int n0 = chunk * 256;

    float4 acc = {0.f, 0.f, 0.f, 0.f};
    float msum = 0.f;
#pragma unroll
    for (int half = 0; half < 2; ++half) {
        float4 v[8];
        float m[8];
#pragma unroll
        for (int j = 0; j < 8; ++j) {
            const int n = n0 + half * 128 + j * 16 + r;
            v[j] = *(const float4*)(qb + (size_t)n * CC + c4 * 4);
            m[j] = mb[(size_t)n * CC];  // channel-0 of broadcast mask
        }
#pragma unroll
        for (int j = 0; j < 8; ++j) {
            acc.x += m[j] * v[j].x; acc.y += m[j] * v[j].y;
            acc.z += m[j] * v[j].z; acc.w += m[j] * v[j].w;
            msum += m[j];
            if (c4 == 0) wmask[n0 + half * 128 + j * 16 + r] = m[j];
        }
    }

    __shared__ float red[16][64];
    __shared__ float wsum[4];
    *(float4*)&red[r][c4 * 4] = acc;
    // wave reduce the (x16 duplicated) mask sum
    for (int off = 32; off > 0; off >>= 1) msum += __shfl_down(msum, off, 64);
    if ((tid & 63) == 0) wsum[tid >> 6] = msum;
    __syncthreads();
    if (tid < 64) {
        float s = 0.f;
#pragma unroll
        for (int rr = 0; rr < 16; ++rr) s += red[rr][tid];
        ws[WS_SUMQ + (b * 8 + chunk) * 64 + tid] = s;  // per-chunk slot, no atomic
    }
    if (tid == 0) {
        ws[WS_SUMM + b * 8 + chunk] =
            (wsum[0] + wsum[1] + wsum[2] + wsum[3]) * (1.f / 16.f);
    }
}

// ---------------- K2: attention (qproj fused as prologue; per-chunk partials) -------
// 2048 blocks (B*8), 1 row per thread. Prologue recomputes q_avg/q/kq per block
// (tiny: ~6K FMAs) -- removes the old 1-wave/CU k_qproj kernel + its launch gap.
// Phase-A m_data loads for the first half are issued BEFORE the prologue so HBM
// latency hides under it.
__global__ __launch_bounds__(256) void k_attn(const float* __restrict__ md,
                                              const float* __restrict__ qw,
                                              const float* __restrict__ kw,
                                              const float* __restrict__ vw,
                                              float* __restrict__ ws) {
    const int b = blockIdx.x >> 3, chunk = blockIdx.x & 7;
    const int tid = threadIdx.x;

    __shared__ float qa[64], ql[64];
    __shared__ float wkv[64][16];  // [c][0..7]=kq, [c][8..15]=vw
    __shared__ float P[256][9];    // +1 pad: stride 9 words, gcd(9,32)=1 -> free writes
    __shared__ float Vv[256][9];
    __shared__ float partV[4][64];
    __shared__ float partS[4][8];

    // ---- issue first half of this thread's row loads early (independent of prologue)
    const int n = chunk * 256 + tid;
    const float* rowp = md + ((size_t)b * NN + n) * CC;
    const float mk = ws[WS_MASK + (size_t)b * NN + n];
    float4 buf[8];
#pragma unroll
    for (int j = 0; j < 8; ++j) buf[j] = ((const float4*)rowp)[j];

    // ---- prologue: q_avg -> q -> kq (replaces old k_qproj kernel)
    if (tid < 64) {
        float s = 0.f, den = 0.f;
#pragma unroll
        for (int ch = 0; ch < 8; ++ch) {
            s += ws[WS_SUMQ + (b * 8 + ch) * 64 + tid];
            den += ws[WS_SUMM + b * 8 + ch];
        }
        qa[tid] = s / (den + 1e-10f);
    }
    __syncthreads();
    if (tid < 64) {
        float s = 0.f;
#pragma unroll
        for (int c = 0; c < 64; ++c) s += qa[c] * qw[c * 64 + tid];
        ql[tid] = s * 0.35355339059327373f;  // KD^-0.5, KD=8
    }
    __syncthreads();
    for (int i = tid; i < 512; i += 256) {
        const int c = i >> 3, h = i & 7;
        float s = 0.f;
#pragma unroll
        for (int d = 0; d < 8; ++d) s += kw[c * 8 + d] * ql[h * 8 + d];
        wkv[c][h] = s;
        wkv[c][8 + h] = vw[i];  // i = c*8+h -> vw[c][h]
    }
    __syncthreads();

    // ---- phase A: logits + v-projection for this thread's row, 8-deep batches
    float la[8], va[8];
#pragma unroll
    for (int h = 0; h < 8; ++h) { la[h] = 0.f; va[h] = 0.f; }
#pragma unroll
    for (int half = 0; half < 2; ++half) {
        if (half == 1) {
#pragma unroll
            for (int j = 0; j < 8; ++j) buf[j] = ((const float4*)rowp)[8 + j];
        }
#pragma unroll
        for (int j = 0; j < 8; ++j) {
            const float xa[4] = {buf[j].x, buf[j].y, buf[j].z, buf[j].w};
#pragma unroll
            for (int q = 0; q < 4; ++q) {
                const int c = half * 32 + j * 4 + q;
                const float4* wr = (const float4*)wkv[c];  // broadcast reads
                const float4 wa = wr[0], wb = wr[1], wc = wr[2], wd = wr[3];
                const float x = xa[q];
                la[0] += x * wa.x; la[1] += x * wa.y; la[2] += x * wa.z; la[3] += x * wa.w;
                la[4] += x * wb.x; la[5] += x * wb.y; la[6] += x * wb.z; la[7] += x * wb.w;
                va[0] += x * wc.x; va[1] += x * wc.y; va[2] += x * wc.z; va[3] += x * wc.w;
                va[4] += x * wd.x; va[5] += x * wd.y; va[6] += x * wd.z; va[7] += x * wd.w;
            }
        }
    }

#pragma unroll
    for (int h = 0; h < 8; ++h) P[tid][h] = mk * __expf(la[h]);  // masked rows -> 0
#pragma unroll
    for (int d = 0; d < 8; ++d) Vv[tid][d] = va[d];
    __syncthreads();

    // ---- phase B: reduce 256 rows -> per-chunk S[h], V[h][d]
    const int w = tid >> 6, lane = tid & 63, h = lane >> 3, d = lane & 7;
    float acc = 0.f, sacc = 0.f;
    for (int i = 0; i < 64; ++i) {
        const int rr = w * 64 + i;
        const float p = P[rr][h];  // 8 distinct words/iter, consecutive banks, bcast x8
        acc += p * Vv[rr][d];
        sacc += p;
    }
    partV[w][lane] = acc;
    if (d == 0) partS[w][h] = sacc;
    __syncthreads();
    if (tid < 64)
        ws[WS_V + (b * 8 + chunk) * 64 + tid] =
            partV[0][tid] + partV[1][tid] + partV[2][tid] + partV[3][tid];
    if (tid < 8)
        ws[WS_S + (b * 8 + chunk) * 8 + tid] =
            partS[0][tid] + partS[1][tid] + partS[2][tid] + partS[3][tid];
}

// ---------------- K4: gate = sigmoid(q_data@Gw + gb); out = (gate*wavg)@Ow + ob ----
// MFMA 16x16x32 bf16. Unchanged from the 485us version except the prologue now
// sums the 8 per-chunk V/S partials into LDS (atomics+memset removed upstream).
__global__ __launch_bounds__(256) void k_out(const float* __restrict__ qd,
                                             const float* __restrict__ ow,
                                             const float* __restrict__ obias,
                                             const float* __restrict__ gw,
                                             const float* __restrict__ gb,
                                             const float* __restrict__ ws,
                                             float* __restrict__ out) {
    const int b = blockIdx.x >> 3, chunk = blockIdx.x & 7;
    const int tid = threadIdx.x;
    const int w = tid >> 6, lane = tid & 63, q16 = lane >> 4, c16 = lane & 15;

    __shared__ float s_wavg[64], s_sden[8];
    if (tid < 64) {
        float s = 0.f;
#pragma unroll
        for (int ch = 0; ch < 8; ++ch) s += ws[WS_V + (b * 8 + ch) * 64 + tid];
        s_wavg[tid] = s;
    }
    if (tid >= 64 && tid < 72) {
        const int hh = tid - 64;
        float s = 0.f;
#pragma unroll
        for (int ch = 0; ch < 8; ++ch) s += ws[WS_S + (b * 8 + ch) * 8 + hh];
        s_sden[hh] = s;
    }
    __syncthreads();

    // Per-wave constant B-fragments: Gw (gating weights) and W2 = wavg ⊙ Ow
    bf16x8 gwf[2][4], w2f[2][4];
    float gbv[4], obv[4];
#pragma unroll
    for (int kc = 0; kc < 2; ++kc) {
        const int k0 = kc * 32 + q16 * 8;
        const float inv_s = 1.f / s_sden[k0 >> 3];  // same h for all 8 j's
#pragma unroll
        for (int t = 0; t < 4; ++t) {
            const int n2 = t * 16 + c16;
            bf16x8 gf, wf;
#pragma unroll
            for (int j = 0; j < 8; ++j) {
                gf[j] = (__bf16)gw[(size_t)(k0 + j) * 64 + n2];
                wf[j] = (__bf16)(s_wavg[k0 + j] * inv_s *
                                 ow[(size_t)(k0 + j) * 64 + n2]);
            }
            gwf[kc][t] = gf;
            w2f[kc][t] = wf;
        }
    }
#pragma unroll
    for (int t = 0; t < 4; ++t) {
        gbv[t] = gb[t * 16 + c16];
        obv[t] = obias[t * 16 + c16];
    }

    // C-layout -> A-layout transpose buffer; wave-private region gl[w];
    // row padded 64->72 bf16 (144B) to spread banks
    __shared__ __align__(16) __bf16 gl[4][16][72];

    const size_t base_row = (size_t)b * NN + chunk * 256 + w * 16;

    float4 cur0, cur1, cur2, cur3, nxt0, nxt1, nxt2, nxt3;
    {
        const float* arow = qd + (base_row + c16) * CC;
        cur0 = *(const float4*)(arow + q16 * 8);
        cur1 = *(const float4*)(arow + q16 * 8 + 4);
        cur2 = *(const float4*)(arow + 32 + q16 * 8);
        cur3 = *(const float4*)(arow + 32 + q16 * 8 + 4);
    }

    for (int s = 0; s < 4; ++s) {
        if (s < 3) {  // prefetch next slab
            const float* arow = qd + (base_row + (s + 1) * 64 + c16) * CC;
            nxt0 = *(const float4*)(arow + q16 * 8);
            nxt1 = *(const float4*)(arow + q16 * 8 + 4);
            nxt2 = *(const float4*)(arow + 32 + q16 * 8);
            nxt3 = *(const float4*)(arow + 32 + q16 * 8 + 4);
        }
        bf16x8 af[2];
        {
            bf16x8 a;
            a[0] = (__bf16)cur0.x; a[1] = (__bf16)cur0.y; a[2] = (__bf16)cur0.z; a[3] = (__bf16)cur0.w;
            a[4] = (__bf16)cur1.x; a[5] = (__bf16)cur1.y; a[6] = (__bf16)cur1.z; a[7] = (__bf16)cur1.w;
            af[0] = a;
            a[0] = (__bf16)cur2.x; a[1] = (__bf16)cur2.y; a[2] = (__bf16)cur2.z; a[3] = (__bf16)cur2.w;
            a[4] = (__bf16)cur3.x; a[5] = (__bf16)cur3.y; a[6] = (__bf16)cur3.z; a[7] = (__bf16)cur3.w;
            af[1] = a;
        }
        f32x4 accg[4] = {{0.f, 0.f, 0.f, 0.f}, {0.f, 0.f, 0.f, 0.f},
                         {0.f, 0.f, 0.f, 0.f}, {0.f, 0.f, 0.f, 0.f}};
#pragma unroll
        for (int kc = 0; kc < 2; ++kc)
#pragma unroll
            for (int t = 0; t < 4; ++t)
                accg[t] = __builtin_amdgcn_mfma_f32_16x16x32_bf16(af[kc], gwf[kc][t],
                                                                  accg[t], 0, 0, 0);
        // sigmoid + stash in A-operand order (wave-private LDS region)
#pragma unroll
        for (int t = 0; t < 4; ++t)
#pragma unroll
            for (int r2 = 0; r2 < 4; ++r2) {
                const float x = accg[t][r2] + gbv[t];
                const float g = 1.f / (1.f + __expf(-x));
                gl[w][q16 * 4 + r2][t * 16 + c16] = (__bf16)g;
            }
        __asm__ volatile("s_waitcnt lgkmcnt(0)" ::: "memory");
        bf16x8 a2[2];
#pragma unroll
        for (int kc = 0; kc < 2; ++kc)
            a2[kc] = *(const bf16x8*)&gl[w][c16][kc * 32 + q16 * 8];
        f32x4 acco[4] = {{0.f, 0.f, 0.f, 0.f}, {0.f, 0.f, 0.f, 0.f},
                         {0.f, 0.f, 0.f, 0.f}, {0.f, 0.f, 0.f, 0.f}};
#pragma unroll
        for (int kc = 0; kc < 2; ++kc)
#pragma unroll
            for (int t = 0; t < 4; ++t)
                acco[t] = __builtin_amdgcn_mfma_f32_16x16x32_bf16(a2[kc], w2f[kc][t],
                                                                  acco[t], 0, 0, 0);
        __asm__ volatile("s_waitcnt lgkmcnt(0)" ::: "memory");  // reads done before next slab's writes
        float* orow = out + (base_row + s * 64) * CC;
#pragma unroll
        for (int t = 0; t < 4; ++t)
#pragma unroll
            for (int r2 = 0; r2 < 4; ++r2)
                orow[(size_t)(q16 * 4 + r2) * 64 + t * 16 + c16] = acco[t][r2] + obv[t];
        cur0 = nxt0; cur1 = nxt1; cur2 = nxt2; cur3 = nxt3;
    }
}

extern "C" void kernel_launch(void* const* d_in, const int* in_sizes, int n_in,
                              void* d_out, int out_size, void* d_ws, size_t ws_size,
                              hipStream_t stream) {
    const float* q_data = (const float*)d_in[0];
    const float* m_data = (const float*)d_in[1];
    const float* q_mask = (const float*)d_in[2];
    // d_in[3] = bias, ignored by the forward (AF2 quirk)
    const float* q_w = (const float*)d_in[4];
    const float* k_w = (const float*)d_in[5];
    const float* v_w = (const float*)d_in[6];
    const float* o_w = (const float*)d_in[7];
    const float* o_b = (const float*)d_in[8];
    const float* g_w = (const float*)d_in[9];
    const float* g_b = (const float*)d_in[10];
    float* out = (float*)d_out;
    float* ws = (float*)d_ws;

    // no memset: every ws region is written (non-atomically) before it is read
    hipLaunchKernelGGL(k_pool, dim3(BN * NCH), dim3(256), 0, stream, q_data, q_mask, ws);
    hipLaunchKernelGGL(k_attn, dim3(BN * NCH), dim3(256), 0, stream, m_data, q_w, k_w,
                       v_w, ws);
    hipLaunchKernelGGL(k_out, dim3(BN * NCH), dim3(256), 0, stream, q_data, o_w, o_b,
                       g_w, g_b, ws, out);
}